// Round 1
// baseline (664.285 us; speedup 1.0000x reference)
//
#include <hip/hip_runtime.h>
#include <hip/hip_bf16.h>
#include <math.h>

#define B_   4
#define T_   4096
#define DIN_ 1024
#define H_   16
#define D_   64
#define M_   (B_*T_)      // 16384
#define N_   (H_*D_*2)    // 2048
#define K_   DIN_         // 1024

typedef unsigned short u16;
typedef __attribute__((ext_vector_type(8))) short short8_t;
typedef __attribute__((ext_vector_type(4))) float float4_t;

__device__ __forceinline__ u16 f2bf(float f) {
  unsigned int x = __float_as_uint(f);
  x += 0x7fffu + ((x >> 16) & 1u);   // round-to-nearest-even (finite inputs)
  return (u16)(x >> 16);
}
__device__ __forceinline__ float bf2f(unsigned int u) {
  return __uint_as_float((u & 0xffffu) << 16);
}

// ---------------- cast fp32 -> bf16, 8 elems/thread ----------------
__global__ void cast_f32_to_bf16(const float4* __restrict__ src,
                                 uint4* __restrict__ dst, int n8) {
  int i = blockIdx.x * blockDim.x + threadIdx.x;
  if (i >= n8) return;
  float4 a = src[2*i], b = src[2*i+1];
  uint4 o;
  o.x = (unsigned)f2bf(a.x) | ((unsigned)f2bf(a.y) << 16);
  o.y = (unsigned)f2bf(a.z) | ((unsigned)f2bf(a.w) << 16);
  o.z = (unsigned)f2bf(b.x) | ((unsigned)f2bf(b.y) << 16);
  o.w = (unsigned)f2bf(b.z) | ((unsigned)f2bf(b.w) << 16);
  dst[i] = o;
}

// ---------------- GEMM: C[M,N] = A[M,K] * B[K,N], relu, split k/v ----------------
// 128x128 tile, BK=32, 256 threads = 4 waves in 2x2, each wave 64x64 (4x4 MFMA tiles)
__global__ __launch_bounds__(256)
void gemm_kv(const u16* __restrict__ A, const u16* __restrict__ Bm,
             u16* __restrict__ kbuf, u16* __restrict__ vbuf) {
  __shared__ u16 lA[128][32];   // [m][k], k contiguous
  __shared__ u16 lB[128][40];   // [n][k] transposed, +8 pad (keeps 16B align)
  const int tid  = threadIdx.x;
  const int wave = tid >> 6;
  const int lane = tid & 63;
  const int quad = lane >> 4;
  const int l16  = lane & 15;
  const int bm = blockIdx.x * 128;
  const int bn = blockIdx.y * 128;
  const int wm = (wave >> 1) * 64;
  const int wn = (wave & 1) * 64;

  const int arow = tid >> 2;          // 0..63
  const int acol = (tid & 3) * 8;     // 0,8,16,24
  const int bnn  = tid & 127;         // n within tile
  const int bkh  = (tid >> 7) * 16;   // k half

  float4_t acc[4][4] = {};

  const u16* Abase0 = A + (size_t)(bm + arow) * K_ + acol;
  const u16* Abase1 = Abase0 + (size_t)64 * K_;
  const u16* Bbase  = Bm + (size_t)bkh * N_ + bn + bnn;

  for (int k0 = 0; k0 < K_; k0 += 32) {
    uint4 a0 = *(const uint4*)(Abase0 + k0);
    uint4 a1 = *(const uint4*)(Abase1 + k0);
    u16 br[16];
#pragma unroll
    for (int j = 0; j < 16; ++j) br[j] = Bbase[(size_t)(k0 + j) * N_];

    __syncthreads();
    *(uint4*)&lA[arow][acol]      = a0;
    *(uint4*)&lA[arow + 64][acol] = a1;
    uint4 b0, b1;
    b0.x = br[0]  | ((unsigned)br[1]  << 16);
    b0.y = br[2]  | ((unsigned)br[3]  << 16);
    b0.z = br[4]  | ((unsigned)br[5]  << 16);
    b0.w = br[6]  | ((unsigned)br[7]  << 16);
    b1.x = br[8]  | ((unsigned)br[9]  << 16);
    b1.y = br[10] | ((unsigned)br[11] << 16);
    b1.z = br[12] | ((unsigned)br[13] << 16);
    b1.w = br[14] | ((unsigned)br[15] << 16);
    *(uint4*)&lB[bnn][bkh]     = b0;
    *(uint4*)&lB[bnn][bkh + 8] = b1;
    __syncthreads();

    short8_t af[4], bfr[4];
#pragma unroll
    for (int i = 0; i < 4; ++i)
      af[i] = *(const short8_t*)&lA[wm + i*16 + l16][quad*8];
#pragma unroll
    for (int j = 0; j < 4; ++j)
      bfr[j] = *(const short8_t*)&lB[wn + j*16 + l16][quad*8];
#pragma unroll
    for (int i = 0; i < 4; ++i)
#pragma unroll
      for (int j = 0; j < 4; ++j)
        acc[i][j] = __builtin_amdgcn_mfma_f32_16x16x32_bf16(af[i], bfr[j], acc[i][j], 0, 0, 0);
  }

  // epilogue: relu, de-interleave k2 -> kbuf/vbuf, bf16 store
  // C/D layout: col(n) = lane&15, row(m) = quad*4 + reg
#pragma unroll
  for (int j = 0; j < 4; ++j) {
    int n   = bn + wn + j*16 + l16;
    int h   = n >> 7;
    int rem = n & 127;
    int d   = rem >> 1;
    u16* dst = (rem & 1) ? vbuf : kbuf;
#pragma unroll
    for (int i = 0; i < 4; ++i) {
#pragma unroll
      for (int r = 0; r < 4; ++r) {
        int m = bm + wm + i*16 + quad*4 + r;
        float val = acc[i][j][r];
        val = val > 0.f ? val : 0.f;
        dst[(size_t)m * (H_*D_) + h * D_ + d] = f2bf(val);
      }
    }
  }
}

// ---------------- s[b,h,t] = sum_d q[h,d]*k[b,t,h,d] ----------------
// one wave per (b,t) row; lane: h = lane>>2, 16 d's per lane
__global__ void compute_s(const u16* __restrict__ kbuf, const float* __restrict__ q,
                          float* __restrict__ sbuf) {
  int row  = blockIdx.x * 4 + (threadIdx.x >> 6);   // b*T + t
  int lane = threadIdx.x & 63;
  int h    = lane >> 2;
  int d0   = (lane & 3) * 16;
  const u16*  kr = kbuf + (size_t)row * (H_*D_) + h * D_ + d0;
  const float* qr = q + h * D_ + d0;
  uint4 p0 = *(const uint4*)kr;
  uint4 p1 = *(const uint4*)(kr + 8);
  float4 q0 = *(const float4*)qr;
  float4 q1 = *(const float4*)(qr + 4);
  float4 q2 = *(const float4*)(qr + 8);
  float4 q3 = *(const float4*)(qr + 12);
  float sum = 0.f;
  sum += bf2f(p0.x) * q0.x + bf2f(p0.x >> 16) * q0.y;
  sum += bf2f(p0.y) * q0.z + bf2f(p0.y >> 16) * q0.w;
  sum += bf2f(p0.z) * q1.x + bf2f(p0.z >> 16) * q1.y;
  sum += bf2f(p0.w) * q1.z + bf2f(p0.w >> 16) * q1.w;
  sum += bf2f(p1.x) * q2.x + bf2f(p1.x >> 16) * q2.y;
  sum += bf2f(p1.y) * q2.z + bf2f(p1.y >> 16) * q2.w;
  sum += bf2f(p1.z) * q3.x + bf2f(p1.z >> 16) * q3.y;
  sum += bf2f(p1.w) * q3.z + bf2f(p1.w >> 16) * q3.w;
  sum += __shfl_xor(sum, 1);
  sum += __shfl_xor(sum, 2);
  if ((lane & 3) == 0) {
    int b = row >> 12;            // T_ = 4096
    int t = row & (T_ - 1);
    sbuf[(size_t)(b * H_ + h) * T_ + t] = sum;
  }
}

// ---------------- online-softmax scan over t, per (b,h) chain ----------------
__global__ void scan_kernel(const u16* __restrict__ vbuf, const float* __restrict__ sbuf,
                            float* __restrict__ partial) {
  int bh = blockIdx.x;            // b*16 + h
  int b  = bh >> 4, h = bh & 15;
  int d  = threadIdx.x;           // 64 threads
  const float* sp = sbuf + (size_t)bh * T_;
  const u16*   vp = vbuf + (size_t)b * T_ * (H_*D_) + h * D_ + d;
  float* pp = partial + (size_t)bh * T_ * D_ + d;
  float m = -INFINITY, u = 0.f, w = 0.f;
#pragma unroll 4
  for (int t = 0; t < T_; ++t) {
    float s = sp[t];
    float v = bf2f(vp[(size_t)t * (H_*D_)]);
    float mn    = fmaxf(m, s);
    float alpha = __expf(m - mn);
    float p     = __expf(s - mn);
    u = u * alpha + p;
    w = w * alpha + p * v;
    m = mn;
    pp[(size_t)t * D_] = __fdividef(w, u);
  }
}

// ---------------- out[b,t,d] = sum_h partial[b,h,t,d] ----------------
__global__ void reduce_h(const float* __restrict__ partial, float* __restrict__ out) {
  int idx = blockIdx.x * 256 + threadIdx.x;   // over B*T*D
  int d = idx & (D_ - 1);
  int t = (idx >> 6) & (T_ - 1);
  int b = idx >> 18;
  const float* p = partial + ((size_t)b * H_ * T_ + t) * D_ + d;
  float s = 0.f;
#pragma unroll
  for (int h = 0; h < H_; ++h) s += p[(size_t)h * T_ * D_];
  out[idx] = s;
}

extern "C" void kernel_launch(void* const* d_in, const int* in_sizes, int n_in,
                              void* d_out, int out_size, void* d_ws, size_t ws_size,
                              hipStream_t stream) {
  const float* inputs = (const float*)d_in[0];   // (B,T,DIN)
  const float* kvk    = (const float*)d_in[1];   // (DIN,H,D,2)
  const float* qk     = (const float*)d_in[2];   // (H,D)
  float* out = (float*)d_out;
  char* ws = (char*)d_ws;

  u16*   aB   = (u16*)ws;                       // 33,554,432 B  inputs bf16
  u16*   wB   = (u16*)(ws + 33554432);          //  4,194,304 B  weights bf16
  u16*   kb   = (u16*)(ws + 37748736);          // 33,554,432 B  k bf16 [M][H*D]
  u16*   vb   = (u16*)(ws + 71303168);          // 33,554,432 B  v bf16 [M][H*D]
  float* sb   = (float*)(ws + 104857600);       //  1,048,576 B  s [B][H][T]
  float* part = (float*)(ws + 105906176);       // 67,108,864 B  partial [B][H][T][D]

  cast_f32_to_bf16<<<8192, 256, 0, stream>>>((const float4*)inputs, (uint4*)aB, M_*K_/8);
  cast_f32_to_bf16<<<1024, 256, 0, stream>>>((const float4*)kvk,    (uint4*)wB, K_*N_/8);
  gemm_kv<<<dim3(M_/128, N_/128), 256, 0, stream>>>(aB, wB, kb, vb);
  compute_s<<<M_/4, 256, 0, stream>>>(kb, qk, sb);
  scan_kernel<<<B_*H_, 64, 0, stream>>>(vb, sb, part);
  reduce_h<<<(B_*T_*D_)/256, 256, 0, stream>>>(part, out);
}

// Round 2
// 313.589 us; speedup vs baseline: 2.1183x; 2.1183x over previous
//
#include <hip/hip_runtime.h>
#include <hip/hip_bf16.h>
#include <math.h>

#define B_   4
#define T_   4096
#define DIN_ 1024
#define H_   16
#define D_   64
#define M_   (B_*T_)      // 16384
#define N_   (H_*D_*2)    // 2048
#define K_   DIN_         // 1024
#define C_   64           // scan chunks per (b,h) chain
#define CL_  (T_/C_)      // 64 steps per chunk

typedef unsigned short u16;
typedef __attribute__((ext_vector_type(8))) short short8_t;
typedef __attribute__((ext_vector_type(4))) float float4_t;

__device__ __forceinline__ u16 f2bf(float f) {
  unsigned int x = __float_as_uint(f);
  x += 0x7fffu + ((x >> 16) & 1u);   // round-to-nearest-even (finite inputs)
  return (u16)(x >> 16);
}
__device__ __forceinline__ float bf2f(unsigned int u) {
  return __uint_as_float((u & 0xffffu) << 16);
}

// ---------------- cast fp32 -> bf16, 8 elems/thread ----------------
__global__ void cast_f32_to_bf16(const float4* __restrict__ src,
                                 uint4* __restrict__ dst, int n8) {
  int i = blockIdx.x * blockDim.x + threadIdx.x;
  if (i >= n8) return;
  float4 a = src[2*i], b = src[2*i+1];
  uint4 o;
  o.x = (unsigned)f2bf(a.x) | ((unsigned)f2bf(a.y) << 16);
  o.y = (unsigned)f2bf(a.z) | ((unsigned)f2bf(a.w) << 16);
  o.z = (unsigned)f2bf(b.x) | ((unsigned)f2bf(b.y) << 16);
  o.w = (unsigned)f2bf(b.z) | ((unsigned)f2bf(b.w) << 16);
  dst[i] = o;
}

// ---------------- GEMM: C[M,N] = A[M,K] * B[K,N], relu, split k/v ----------------
// 128x128 tile, BK=32, 256 threads = 4 waves in 2x2, each wave 64x64 (4x4 MFMA tiles)
// k written [b,t,h,d] (for compute_s row reads); v written [b,h,t,d] (for scan streaming)
__global__ __launch_bounds__(256)
void gemm_kv(const u16* __restrict__ A, const u16* __restrict__ Bm,
             u16* __restrict__ kbuf, u16* __restrict__ vbuf) {
  __shared__ u16 lA[128][32];   // [m][k], k contiguous
  __shared__ u16 lB[128][40];   // [n][k] transposed, +8 pad (keeps 16B align)
  const int tid  = threadIdx.x;
  const int wave = tid >> 6;
  const int lane = tid & 63;
  const int quad = lane >> 4;
  const int l16  = lane & 15;
  const int bm = blockIdx.x * 128;
  const int bn = blockIdx.y * 128;
  const int wm = (wave >> 1) * 64;
  const int wn = (wave & 1) * 64;

  const int arow = tid >> 2;          // 0..63
  const int acol = (tid & 3) * 8;     // 0,8,16,24
  const int bnn  = tid & 127;         // n within tile
  const int bkh  = (tid >> 7) * 16;   // k half

  float4_t acc[4][4] = {};

  const u16* Abase0 = A + (size_t)(bm + arow) * K_ + acol;
  const u16* Abase1 = Abase0 + (size_t)64 * K_;
  const u16* Bbase  = Bm + (size_t)bkh * N_ + bn + bnn;

  for (int k0 = 0; k0 < K_; k0 += 32) {
    uint4 a0 = *(const uint4*)(Abase0 + k0);
    uint4 a1 = *(const uint4*)(Abase1 + k0);
    u16 br[16];
#pragma unroll
    for (int j = 0; j < 16; ++j) br[j] = Bbase[(size_t)(k0 + j) * N_];

    __syncthreads();
    *(uint4*)&lA[arow][acol]      = a0;
    *(uint4*)&lA[arow + 64][acol] = a1;
    uint4 b0, b1;
    b0.x = br[0]  | ((unsigned)br[1]  << 16);
    b0.y = br[2]  | ((unsigned)br[3]  << 16);
    b0.z = br[4]  | ((unsigned)br[5]  << 16);
    b0.w = br[6]  | ((unsigned)br[7]  << 16);
    b1.x = br[8]  | ((unsigned)br[9]  << 16);
    b1.y = br[10] | ((unsigned)br[11] << 16);
    b1.z = br[12] | ((unsigned)br[13] << 16);
    b1.w = br[14] | ((unsigned)br[15] << 16);
    *(uint4*)&lB[bnn][bkh]     = b0;
    *(uint4*)&lB[bnn][bkh + 8] = b1;
    __syncthreads();

    short8_t af[4], bfr[4];
#pragma unroll
    for (int i = 0; i < 4; ++i)
      af[i] = *(const short8_t*)&lA[wm + i*16 + l16][quad*8];
#pragma unroll
    for (int j = 0; j < 4; ++j)
      bfr[j] = *(const short8_t*)&lB[wn + j*16 + l16][quad*8];
#pragma unroll
    for (int i = 0; i < 4; ++i)
#pragma unroll
      for (int j = 0; j < 4; ++j)
        acc[i][j] = __builtin_amdgcn_mfma_f32_16x16x32_bf16(af[i], bfr[j], acc[i][j], 0, 0, 0);
  }

  // epilogue: relu, de-interleave -> kbuf [m][h*64+d] / vbuf [b][h][t][d]
  // C/D layout: col(n) = lane&15, row(m) = quad*4 + reg
#pragma unroll
  for (int j = 0; j < 4; ++j) {
    int n   = bn + wn + j*16 + l16;
    int h   = n >> 7;
    int rem = n & 127;
    int d   = rem >> 1;
    bool isv = (rem & 1) != 0;
#pragma unroll
    for (int i = 0; i < 4; ++i) {
#pragma unroll
      for (int r = 0; r < 4; ++r) {
        int m = bm + wm + i*16 + quad*4 + r;
        float val = acc[i][j][r];
        val = val > 0.f ? val : 0.f;
        size_t kidx = (size_t)m * (H_*D_) + h * D_ + d;
        size_t vidx = (((size_t)(m >> 12) * H_ + h) * T_ + (m & (T_-1))) * D_ + d;
        u16* dst = isv ? vbuf : kbuf;
        dst[isv ? vidx : kidx] = f2bf(val);
      }
    }
  }
}

// ---------------- s[b,h,t] = sum_d q[h,d]*k[b,t,h,d] ----------------
// one wave per (b,t) row; lane: h = lane>>2, 16 d's per lane
__global__ void compute_s(const u16* __restrict__ kbuf, const float* __restrict__ q,
                          float* __restrict__ sbuf) {
  int row  = blockIdx.x * 4 + (threadIdx.x >> 6);   // b*T + t
  int lane = threadIdx.x & 63;
  int h    = lane >> 2;
  int d0   = (lane & 3) * 16;
  const u16*  kr = kbuf + (size_t)row * (H_*D_) + h * D_ + d0;
  const float* qr = q + h * D_ + d0;
  uint4 p0 = *(const uint4*)kr;
  uint4 p1 = *(const uint4*)(kr + 8);
  float4 q0 = *(const float4*)qr;
  float4 q1 = *(const float4*)(qr + 4);
  float4 q2 = *(const float4*)(qr + 8);
  float4 q3 = *(const float4*)(qr + 12);
  float sum = 0.f;
  sum += bf2f(p0.x) * q0.x + bf2f(p0.x >> 16) * q0.y;
  sum += bf2f(p0.y) * q0.z + bf2f(p0.y >> 16) * q0.w;
  sum += bf2f(p0.z) * q1.x + bf2f(p0.z >> 16) * q1.y;
  sum += bf2f(p0.w) * q1.z + bf2f(p0.w >> 16) * q1.w;
  sum += bf2f(p1.x) * q2.x + bf2f(p1.x >> 16) * q2.y;
  sum += bf2f(p1.y) * q2.z + bf2f(p1.y >> 16) * q2.w;
  sum += bf2f(p1.z) * q3.x + bf2f(p1.z >> 16) * q3.y;
  sum += bf2f(p1.w) * q3.z + bf2f(p1.w >> 16) * q3.w;
  sum += __shfl_xor(sum, 1);
  sum += __shfl_xor(sum, 2);
  if ((lane & 3) == 0) {
    int b = row >> 12;            // T_ = 4096
    int t = row & (T_ - 1);
    sbuf[(size_t)(b * H_ + h) * T_ + t] = sum;
  }
}

// ---------------- chunked online-softmax scan, pass 1: chunk aggregates ----------------
// block = one chunk of one (b,h) chain; 64 threads = one d each
__global__ void scan_pass1(const u16* __restrict__ vbuf, const float* __restrict__ sbuf,
                           float* __restrict__ aggM, float* __restrict__ aggU,
                           float* __restrict__ aggW) {
  int blk = blockIdx.x;            // bh*C + c
  int bh  = blk >> 6;
  int c   = blk & (C_ - 1);
  int d   = threadIdx.x;
  int t0  = c * CL_;
  const float* sp = sbuf + (size_t)bh * T_ + t0;
  const u16*   vp = vbuf + ((size_t)bh * T_ + t0) * D_ + d;
  float m = -INFINITY, u = 0.f, w = 0.f;
#pragma unroll 4
  for (int i = 0; i < CL_; ++i) {
    float s = sp[i];
    float v = bf2f(vp[i * D_]);
    float mn    = fmaxf(m, s);
    float alpha = __expf(m - mn);
    float p     = __expf(s - mn);
    u = u * alpha + p;
    w = w * alpha + p * v;
    m = mn;
  }
  aggW[(size_t)blk * D_ + d] = w;
  if (d == 0) { aggM[blk] = m; aggU[blk] = u; }
}

// ---------------- pass 2: exclusive scan of chunk aggregates per chain ----------------
__global__ void scan_pass2(const float* __restrict__ aggM, const float* __restrict__ aggU,
                           const float* __restrict__ aggW,
                           float* __restrict__ preM, float* __restrict__ preU,
                           float* __restrict__ preW) {
  int bh = blockIdx.x;
  int d  = threadIdx.x;
  float m = -INFINITY, u = 0.f, w = 0.f;
  for (int c = 0; c < C_; ++c) {
    int idx = bh * C_ + c;
    preW[(size_t)idx * D_ + d] = w;          // exclusive prefix for chunk c
    if (d == 0) { preM[idx] = m; preU[idx] = u; }
    float Mc = aggM[idx];
    float Uc = aggU[idx];
    float Wc = aggW[(size_t)idx * D_ + d];
    float mn = fmaxf(m, Mc);
    float ea = __expf(m - mn);               // m=-inf, Mc finite -> 0, no NaN
    float eb = __expf(Mc - mn);
    u = u * ea + Uc * eb;
    w = w * ea + Wc * eb;
    m = mn;
  }
}

// ---------------- pass 3: re-scan chunk seeded with prefix, emit w/u ----------------
__global__ void scan_pass3(const u16* __restrict__ vbuf, const float* __restrict__ sbuf,
                           const float* __restrict__ preM, const float* __restrict__ preU,
                           const float* __restrict__ preW, float* __restrict__ partial) {
  int blk = blockIdx.x;
  int bh  = blk >> 6;
  int c   = blk & (C_ - 1);
  int d   = threadIdx.x;
  int t0  = c * CL_;
  const float* sp = sbuf + (size_t)bh * T_ + t0;
  const u16*   vp = vbuf + ((size_t)bh * T_ + t0) * D_ + d;
  float*       pp = partial + ((size_t)bh * T_ + t0) * D_ + d;
  float m = preM[blk], u = preU[blk], w = preW[(size_t)blk * D_ + d];
#pragma unroll 4
  for (int i = 0; i < CL_; ++i) {
    float s = sp[i];
    float v = bf2f(vp[i * D_]);
    float mn    = fmaxf(m, s);
    float alpha = __expf(m - mn);
    float p     = __expf(s - mn);
    u = u * alpha + p;
    w = w * alpha + p * v;
    m = mn;
    pp[i * D_] = __fdividef(w, u);
  }
}

// ---------------- out[b,t,d] = sum_h partial[b,h,t,d] ----------------
__global__ void reduce_h(const float* __restrict__ partial, float* __restrict__ out) {
  int idx = blockIdx.x * 256 + threadIdx.x;   // over B*T*D
  int d = idx & (D_ - 1);
  int t = (idx >> 6) & (T_ - 1);
  int b = idx >> 18;
  const float* p = partial + ((size_t)b * H_ * T_ + t) * D_ + d;
  float s = 0.f;
#pragma unroll
  for (int h = 0; h < H_; ++h) s += p[(size_t)h * T_ * D_];
  out[idx] = s;
}

extern "C" void kernel_launch(void* const* d_in, const int* in_sizes, int n_in,
                              void* d_out, int out_size, void* d_ws, size_t ws_size,
                              hipStream_t stream) {
  const float* inputs = (const float*)d_in[0];   // (B,T,DIN)
  const float* kvk    = (const float*)d_in[1];   // (DIN,H,D,2)
  const float* qk     = (const float*)d_in[2];   // (H,D)
  float* out = (float*)d_out;
  char* ws = (char*)d_ws;

  u16*   aB   = (u16*)ws;                       // 33,554,432 B  inputs bf16
  u16*   wB   = (u16*)(ws + 33554432);          //  4,194,304 B  weights bf16
  u16*   kb   = (u16*)(ws + 37748736);          // 33,554,432 B  k bf16 [b,t,h,d]
  u16*   vb   = (u16*)(ws + 71303168);          // 33,554,432 B  v bf16 [b,h,t,d]
  float* sb   = (float*)(ws + 104857600);       //  1,048,576 B  s [b,h,t]
  float* part = (float*)(ws + 105906176);       // 67,108,864 B  partial [b,h,t,d]
  float* aggM = (float*)(ws + 173015040);       //     16,384 B
  float* aggU = (float*)(ws + 173031424);       //     16,384 B
  float* aggW = (float*)(ws + 173047808);       //  1,048,576 B
  float* preM = (float*)(ws + 174096384);       //     16,384 B
  float* preU = (float*)(ws + 174112768);       //     16,384 B
  float* preW = (float*)(ws + 174129152);       //  1,048,576 B  (ends ~175.2 MB)

  cast_f32_to_bf16<<<8192, 256, 0, stream>>>((const float4*)inputs, (uint4*)aB, M_*K_/8);
  cast_f32_to_bf16<<<1024, 256, 0, stream>>>((const float4*)kvk,    (uint4*)wB, K_*N_/8);
  gemm_kv<<<dim3(M_/128, N_/128), 256, 0, stream>>>(aB, wB, kb, vb);
  compute_s<<<M_/4, 256, 0, stream>>>(kb, qk, sb);
  scan_pass1<<<B_*H_*C_, 64, 0, stream>>>(vb, sb, aggM, aggU, aggW);
  scan_pass2<<<B_*H_, 64, 0, stream>>>(aggM, aggU, aggW, preM, preU, preW);
  scan_pass3<<<B_*H_*C_, 64, 0, stream>>>(vb, sb, preM, preU, preW, part);
  reduce_h<<<(B_*T_*D_)/256, 256, 0, stream>>>(part, out);
}